// Round 9
// baseline (47.201 us; speedup 1.0000x reference)
//
#include <hip/hip_runtime.h>

// B=16, C=4, H=512, W=512 ; rows=64 ; row length=262144 ; k=26214
// answer = sum(topk loss per row) / (64*26214)
//
// Threshold-based top-k sum: f(T) = sum_{l>T} l + (k - N(T))*T has f'(T)=k-N(T)=0
// at the true k-th value => second-order accurate in T error.
// T estimated per row from a 1/16 sample histogram; full pass is a pure stream.
//
// MLP fix history: r7 batched loads -> compiler sank them (VGPR 24->36 only).
// r8 sched_barrier(0) -> no memory semantics, IR sinking moved loads anyway.
// r9: asm volatile("" ::: "memory") (loads may NOT sink past a may-write fence)
//     + sched_barrier(0) (VALU may not hoist above, rule #18). Forces ~64 data
//     VGPRs live -> 256 B/wave outstanding -> latency actually hidden.

#define ROWS 64
#define ROW_N4 65536            // float4 per row
#define K_SEL 26214u
#define THREADS 256
#define BINS 2048               // linear bins over [0,8), width 1/256
#define NSUB 4
#define CHUNK4 2048             // float4 per k_pass block

// fast BCE-with-logits: max(x,0) - x*y + log1p(exp(-|x|))
__device__ __forceinline__ float loss_fast(float x, float y) {
    float a = fabsf(x);
    float t = __builtin_amdgcn_exp2f(a * -1.44269504088896f);       // e^-a
    float sp = 0.69314718055995f * __builtin_amdgcn_logf(1.0f + t); // ln2*log2(1+t)
    return fmaxf(x, 0.0f) - x * y + sp;
}
__device__ __forceinline__ unsigned bin_of(float l) {
    unsigned b = (unsigned)(l * 256.0f);
    return b > (BINS - 1u) ? (BINS - 1u) : b;
}

// Fence: loads issued above may not sink below (asm may-write), compute below
// may not hoist above (sched_barrier, rule #18).
__device__ __forceinline__ void load_fence() {
    asm volatile("" ::: "memory");
    __builtin_amdgcn_sched_barrier(0);
}

// ---------- Phase A: sampled per-row histogram (counts only, 1/16 of data) ----------
__global__ __launch_bounds__(THREADS)
void k_sample(const float4* __restrict__ lg, const float4* __restrict__ tg,
              unsigned* __restrict__ gcnt) {
    __shared__ unsigned h[BINS * NSUB];          // 32 KB
    int t = threadIdx.x;
    for (int i = t; i < BINS * NSUB; i += THREADS) h[i] = 0;
    __syncthreads();

    int row = blockIdx.x >> 2;
    int s = blockIdx.x & 3;
    int sub = t & (NSUB - 1);

    float4 xs[4], ys[4];
#pragma unroll
    for (int i = 0; i < 4; ++i) {
        int idx = row * ROW_N4 + (s * 4 + i) * 4096 + t;
        xs[i] = lg[idx];
        ys[i] = tg[idx];
    }
    load_fence();
#pragma unroll
    for (int i = 0; i < 4; ++i) {
        atomicAdd(&h[bin_of(loss_fast(xs[i].x, ys[i].x)) * NSUB + sub], 1u);
        atomicAdd(&h[bin_of(loss_fast(xs[i].y, ys[i].y)) * NSUB + sub], 1u);
        atomicAdd(&h[bin_of(loss_fast(xs[i].z, ys[i].z)) * NSUB + sub], 1u);
        atomicAdd(&h[bin_of(loss_fast(xs[i].w, ys[i].w)) * NSUB + sub], 1u);
    }
    __syncthreads();
    unsigned* gc = gcnt + row * BINS;
    const uint4* h4 = (const uint4*)h;
    for (int i = t; i < BINS; i += THREADS) {
        uint4 v = h4[i];
        unsigned c = v.x + v.y + v.z + v.w;
        if (c) atomicAdd(&gc[i], c);
    }
}

// ---------- Select per-row threshold T (sample quantile: 26214/16 = 1638) ----------
__global__ __launch_bounds__(THREADS)
void k_sel(const unsigned* __restrict__ gcnt, float* __restrict__ Trow) {
    const unsigned target = 1638u;
    int row = blockIdx.x;
    int t = threadIdx.x;
    __shared__ unsigned h[BINS];
    __shared__ unsigned csum[THREADS];
    for (int i = t; i < BINS; i += THREADS) h[i] = gcnt[row * BINS + i];
    __syncthreads();

    unsigned s = 0;
#pragma unroll
    for (int j = 0; j < 8; ++j) s += h[t * 8 + j];
    csum[t] = s;
    __syncthreads();
    for (int off = 1; off < THREADS; off <<= 1) {
        unsigned add = (t + off < THREADS) ? csum[t + off] : 0;
        __syncthreads();
        csum[t] += add;
        __syncthreads();
    }
    unsigned suffIncl = csum[t];
    unsigned suffExcl = (t + 1 < THREADS) ? csum[t + 1] : 0;
    if (suffExcl < target && suffIncl >= target) {
        unsigned cum = suffExcl;
        for (int j = 7; j >= 0; --j) {
            unsigned c = h[t * 8 + j];
            if (cum + c >= target) {
                Trow[row] = ((float)(t * 8 + j) + 0.5f) * (1.0f / 256.0f);
                break;
            }
            cum += c;
        }
    }
}

// ---------- Full pass: 16 loads pinned in flight, then compare+accumulate ----------
__global__ __launch_bounds__(THREADS)
void k_pass(const float4* __restrict__ lg, const float4* __restrict__ tg,
            const float* __restrict__ Trow,
            double* __restrict__ rowsum, unsigned* __restrict__ rowcnt) {
    __shared__ float red_s[THREADS];
    __shared__ unsigned red_c[THREADS];
    int t = threadIdx.x;
    int row = blockIdx.x >> 5;
    int chunk = blockIdx.x & 31;
    int base = row * ROW_N4 + chunk * CHUNK4;
    float T = Trow[row];

    float4 xs[8], ys[8];
#pragma unroll
    for (int j = 0; j < 8; ++j) {
        int idx = base + j * THREADS + t;
        xs[j] = lg[idx];
        ys[j] = tg[idx];
    }
    load_fence();   // all 16 global_load_dwordx4 stay issued above this point

    float lsum = 0.0f;
    unsigned lcnt = 0;
#pragma unroll
    for (int j = 0; j < 8; ++j) {
        float l0 = loss_fast(xs[j].x, ys[j].x);
        float l1 = loss_fast(xs[j].y, ys[j].y);
        float l2 = loss_fast(xs[j].z, ys[j].z);
        float l3 = loss_fast(xs[j].w, ys[j].w);
        if (l0 > T) { lsum += l0; ++lcnt; }
        if (l1 > T) { lsum += l1; ++lcnt; }
        if (l2 > T) { lsum += l2; ++lcnt; }
        if (l3 > T) { lsum += l3; ++lcnt; }
    }
    red_s[t] = lsum;
    red_c[t] = lcnt;
    __syncthreads();
    for (int off = THREADS / 2; off > 0; off >>= 1) {
        if (t < off) { red_s[t] += red_s[t + off]; red_c[t] += red_c[t + off]; }
        __syncthreads();
    }
    if (t == 0) {
        atomicAdd(&rowsum[row], (double)red_s[0]);
        atomicAdd(&rowcnt[row], red_c[0]);
    }
}

// ---------- Finalize: rowtot = sum_above + (k - N)*T ; mean over rows ----------
__global__ __launch_bounds__(ROWS)
void k_finalize(const double* __restrict__ rowsum, const unsigned* __restrict__ rowcnt,
                const float* __restrict__ Trow, float* __restrict__ out) {
    __shared__ double tot[ROWS];
    int r = threadIdx.x;
    double T = (double)Trow[r];
    double corr = ((double)(int)K_SEL - (double)(int)rowcnt[r]) * T;
    tot[r] = rowsum[r] + corr;
    __syncthreads();
    if (r == 0) {
        double s = 0.0;
        for (int i = 0; i < ROWS; ++i) s += tot[i];
        out[0] = (float)(s / ((double)ROWS * (double)K_SEL));
    }
}

extern "C" void kernel_launch(void* const* d_in, const int* in_sizes, int n_in,
                              void* d_out, int out_size, void* d_ws, size_t ws_size,
                              hipStream_t stream) {
    const float4* lg = (const float4*)d_in[0];
    const float4* tg = (const float4*)d_in[1];
    float* out = (float*)d_out;
    (void)in_sizes; (void)n_in; (void)out_size; (void)ws_size;

    // workspace layout
    char* ws = (char*)d_ws;
    unsigned* gcnt   = (unsigned*)(ws);                  // 64*2048*4 = 524288
    float*    Trow   = (float*)   (ws + 524288);         // 256
    double*   rowsum = (double*)  (ws + 524544);         // 512 (8-aligned)
    unsigned* rowcnt = (unsigned*)(ws + 525056);         // 256
    size_t small_bytes = 525312;

    (void)hipMemsetAsync(d_ws, 0, small_bytes, stream);

    k_sample<<<ROWS * 4, THREADS, 0, stream>>>(lg, tg, gcnt);
    k_sel<<<ROWS, THREADS, 0, stream>>>(gcnt, Trow);
    k_pass<<<ROWS * 32, THREADS, 0, stream>>>(lg, tg, Trow, rowsum, rowcnt);
    k_finalize<<<1, ROWS, 0, stream>>>(rowsum, rowcnt, Trow, out);
}

// Round 10
// 46.021 us; speedup vs baseline: 1.0256x; 1.0256x over previous
//
#include <hip/hip_runtime.h>

// B=16, C=4, H=512, W=512 ; rows=64 ; row length=262144 ; k=26214
// answer = sum(topk loss per row) / (64*26214)
//
// Threshold-based top-k sum: f(T) = sum_{l>T} l + (k - N(T))*T has f'(T)=k-N(T)=0
// at the true k-th value => second-order accurate in T error. T from a 1/16 sample.
//
// MLP history: r6-r9 proved hipcc will not keep >2-3 dwordx4 pairs in VGPRs
// (VGPR stuck at 36; ~3 KB/CU in flight -> 3.2 TB/s). r10: global_load_lds DMA
// staging -- zero VGPR cost, outstanding depth controlled by counted vmcnt.
// Per-wave-private double buffer => NO barriers in the hot loop (vmcnt is
// per-wave; each wave stages and consumes only its own 1KB/stream slice).

#define ROWS 64
#define ROW_N4 65536            // float4 per row
#define K_SEL 26214u
#define THREADS 256
#define BINS 2048               // linear bins over [0,8), width 1/256
#define NSUB 4
#define CHUNK4 2048             // float4 per k_pass block
#define TILE4 256               // float4 per tile per stream (1 per thread)
#define NTILE 8                 // CHUNK4 / TILE4

// fast BCE-with-logits: max(x,0) - x*y + log1p(exp(-|x|))
__device__ __forceinline__ float loss_fast(float x, float y) {
    float a = fabsf(x);
    float t = __builtin_amdgcn_exp2f(a * -1.44269504088896f);       // e^-a
    float sp = 0.69314718055995f * __builtin_amdgcn_logf(1.0f + t); // ln2*log2(1+t)
    return fmaxf(x, 0.0f) - x * y + sp;
}
__device__ __forceinline__ unsigned bin_of(float l) {
    unsigned b = (unsigned)(l * 256.0f);
    return b > (BINS - 1u) ? (BINS - 1u) : b;
}

// async 16B/lane global->LDS DMA; gptr per-lane, lds ptr wave-uniform base
__device__ __forceinline__ void load_lds16(const float4* g, float4* l) {
    __builtin_amdgcn_global_load_lds((const __attribute__((address_space(1))) void*)g,
                                     (__attribute__((address_space(3))) void*)l,
                                     16, 0, 0);
}

// ---------- Phase A: sampled per-row histogram (counts only, 1/16 of data) ----------
__global__ __launch_bounds__(THREADS)
void k_sample(const float4* __restrict__ lg, const float4* __restrict__ tg,
              unsigned* __restrict__ gcnt) {
    __shared__ unsigned h[BINS * NSUB];          // 32 KB
    int t = threadIdx.x;
    for (int i = t; i < BINS * NSUB; i += THREADS) h[i] = 0;
    __syncthreads();

    int row = blockIdx.x >> 2;
    int s = blockIdx.x & 3;
    int sub = t & (NSUB - 1);

    float4 xs[4], ys[4];
#pragma unroll
    for (int i = 0; i < 4; ++i) {
        int idx = row * ROW_N4 + (s * 4 + i) * 4096 + t;
        xs[i] = lg[idx];
        ys[i] = tg[idx];
    }
#pragma unroll
    for (int i = 0; i < 4; ++i) {
        atomicAdd(&h[bin_of(loss_fast(xs[i].x, ys[i].x)) * NSUB + sub], 1u);
        atomicAdd(&h[bin_of(loss_fast(xs[i].y, ys[i].y)) * NSUB + sub], 1u);
        atomicAdd(&h[bin_of(loss_fast(xs[i].z, ys[i].z)) * NSUB + sub], 1u);
        atomicAdd(&h[bin_of(loss_fast(xs[i].w, ys[i].w)) * NSUB + sub], 1u);
    }
    __syncthreads();
    unsigned* gc = gcnt + row * BINS;
    const uint4* h4 = (const uint4*)h;
    for (int i = t; i < BINS; i += THREADS) {
        uint4 v = h4[i];
        unsigned c = v.x + v.y + v.z + v.w;
        if (c) atomicAdd(&gc[i], c);
    }
}

// ---------- Select per-row threshold T (sample quantile: 26214/16 = 1638) ----------
__global__ __launch_bounds__(THREADS)
void k_sel(const unsigned* __restrict__ gcnt, float* __restrict__ Trow) {
    const unsigned target = 1638u;
    int row = blockIdx.x;
    int t = threadIdx.x;
    __shared__ unsigned h[BINS];
    __shared__ unsigned csum[THREADS];
    for (int i = t; i < BINS; i += THREADS) h[i] = gcnt[row * BINS + i];
    __syncthreads();

    unsigned s = 0;
#pragma unroll
    for (int j = 0; j < 8; ++j) s += h[t * 8 + j];
    csum[t] = s;
    __syncthreads();
    for (int off = 1; off < THREADS; off <<= 1) {
        unsigned add = (t + off < THREADS) ? csum[t + off] : 0;
        __syncthreads();
        csum[t] += add;
        __syncthreads();
    }
    unsigned suffIncl = csum[t];
    unsigned suffExcl = (t + 1 < THREADS) ? csum[t + 1] : 0;
    if (suffExcl < target && suffIncl >= target) {
        unsigned cum = suffExcl;
        for (int j = 7; j >= 0; --j) {
            unsigned c = h[t * 8 + j];
            if (cum + c >= target) {
                Trow[row] = ((float)(t * 8 + j) + 0.5f) * (1.0f / 256.0f);
                break;
            }
            cum += c;
        }
    }
}

// ---------- Full pass: DMA-staged double-buffer stream, barrier-free hot loop ----------
__global__ __launch_bounds__(THREADS)
void k_pass(const float4* __restrict__ lg, const float4* __restrict__ tg,
            const float* __restrict__ Trow,
            double* __restrict__ rowsum, unsigned* __restrict__ rowcnt) {
    __shared__ float4 sA[2][TILE4];     // 8 KB  (lg staging)
    __shared__ float4 sB[2][TILE4];     // 8 KB  (tg staging)
    __shared__ float red_s[THREADS];
    __shared__ unsigned red_c[THREADS];

    int t = threadIdx.x;
    int w = t >> 6;                     // wave id 0..3 (wave-private slices)
    int row = blockIdx.x >> 5;
    int chunk = blockIdx.x & 31;
    int base = row * ROW_N4 + chunk * CHUNK4;
    float T = Trow[row];                // uniform -> s_load (lgkmcnt, not vmcnt)

    // prologue: stage tiles 0 and 1 (4 DMA loads/wave in flight)
    load_lds16(lg + base + 0 * TILE4 + t, &sA[0][w * 64]);
    load_lds16(tg + base + 0 * TILE4 + t, &sB[0][w * 64]);
    load_lds16(lg + base + 1 * TILE4 + t, &sA[1][w * 64]);
    load_lds16(tg + base + 1 * TILE4 + t, &sB[1][w * 64]);

    float lsum = 0.0f;
    unsigned lcnt = 0;
    int cur = 0;
#pragma unroll
    for (int tile = 0; tile < NTILE; ++tile) {
        // wait for buf[cur]'s pair; keep next tile's pair in flight (never drain to 0 mid-loop)
        if (tile < NTILE - 1) {
            asm volatile("s_waitcnt vmcnt(2)" ::: "memory");
        } else {
            asm volatile("s_waitcnt vmcnt(0)" ::: "memory");
        }
        __builtin_amdgcn_sched_barrier(0);
        float4 x = sA[cur][t];          // ds_read_b128 of own staged slot
        float4 y = sB[cur][t];
        float l0 = loss_fast(x.x, y.x);
        float l1 = loss_fast(x.y, y.y);
        float l2 = loss_fast(x.z, y.z);
        float l3 = loss_fast(x.w, y.w);
        if (l0 > T) { lsum += l0; ++lcnt; }
        if (l1 > T) { lsum += l1; ++lcnt; }
        if (l2 > T) { lsum += l2; ++lcnt; }
        if (l3 > T) { lsum += l3; ++lcnt; }
        // refill the buffer just consumed with tile+2 (reads已 returned: values consumed above)
        if (tile + 2 < NTILE) {
            load_lds16(lg + base + (tile + 2) * TILE4 + t, &sA[cur][w * 64]);
            load_lds16(tg + base + (tile + 2) * TILE4 + t, &sB[cur][w * 64]);
        }
        cur ^= 1;
    }

    red_s[t] = lsum;
    red_c[t] = lcnt;
    __syncthreads();
    for (int off = THREADS / 2; off > 0; off >>= 1) {
        if (t < off) { red_s[t] += red_s[t + off]; red_c[t] += red_c[t + off]; }
        __syncthreads();
    }
    if (t == 0) {
        atomicAdd(&rowsum[row], (double)red_s[0]);
        atomicAdd(&rowcnt[row], red_c[0]);
    }
}

// ---------- Finalize: rowtot = sum_above + (k - N)*T ; mean over rows ----------
__global__ __launch_bounds__(ROWS)
void k_finalize(const double* __restrict__ rowsum, const unsigned* __restrict__ rowcnt,
                const float* __restrict__ Trow, float* __restrict__ out) {
    __shared__ double tot[ROWS];
    int r = threadIdx.x;
    double T = (double)Trow[r];
    double corr = ((double)(int)K_SEL - (double)(int)rowcnt[r]) * T;
    tot[r] = rowsum[r] + corr;
    __syncthreads();
    if (r == 0) {
        double s = 0.0;
        for (int i = 0; i < ROWS; ++i) s += tot[i];
        out[0] = (float)(s / ((double)ROWS * (double)K_SEL));
    }
}

extern "C" void kernel_launch(void* const* d_in, const int* in_sizes, int n_in,
                              void* d_out, int out_size, void* d_ws, size_t ws_size,
                              hipStream_t stream) {
    const float4* lg = (const float4*)d_in[0];
    const float4* tg = (const float4*)d_in[1];
    float* out = (float*)d_out;
    (void)in_sizes; (void)n_in; (void)out_size; (void)ws_size;

    // workspace layout
    char* ws = (char*)d_ws;
    unsigned* gcnt   = (unsigned*)(ws);                  // 64*2048*4 = 524288
    float*    Trow   = (float*)   (ws + 524288);         // 256
    double*   rowsum = (double*)  (ws + 524544);         // 512 (8-aligned)
    unsigned* rowcnt = (unsigned*)(ws + 525056);         // 256
    size_t small_bytes = 525312;

    (void)hipMemsetAsync(d_ws, 0, small_bytes, stream);

    k_sample<<<ROWS * 4, THREADS, 0, stream>>>(lg, tg, gcnt);
    k_sel<<<ROWS, THREADS, 0, stream>>>(gcnt, Trow);
    k_pass<<<ROWS * 32, THREADS, 0, stream>>>(lg, tg, Trow, rowsum, rowcnt);
    k_finalize<<<1, ROWS, 0, stream>>>(rowsum, rowcnt, Trow, out);
}

// Round 11
// 44.200 us; speedup vs baseline: 1.0679x; 1.0412x over previous
//
#include <hip/hip_runtime.h>

// B=16, C=4, H=512, W=512 ; rows=64 ; row length=262144 ; k=26214
// answer = sum(topk loss per row) / (64*26214)
//
// Threshold-based top-k sum: f(T) = sum_{l>T} l + (k - N(T))*T has f'(T)=k-N(T)=0
// at the true k-th value => second-order accurate in T error. T from a 1/16 sample.
//
// r6-r10: five k_pass variants (plain, VGPR-batched x3, DMA double-buffered) all
// pin at ~3.3 TB/s with NO saturated pipe. Shared invariant: fine-grained (<=1KB)
// alternation between the lg and tg streams -> suspected DRAM row-locality loss.
// r11: wave-private 4KB single-stream DMA bursts (4 consecutive 1KB loads from lg,
// then 4 from tg), compute from LDS. Single-buffered; TLP (20 waves/CU) covers.

#define ROWS 64
#define ROW_N4 65536            // float4 per row
#define K_SEL 26214u
#define THREADS 256
#define BINS 2048               // linear bins over [0,8), width 1/256
#define NSUB 4
#define CHUNK4 2048             // float4 per block per stream (32 KB)
#define WSLICE 512              // float4 per wave per stream
#define TILE4W 256              // float4 per wave per tile per stream (4 KB burst)

// fast BCE-with-logits: max(x,0) - x*y + log1p(exp(-|x|))
__device__ __forceinline__ float loss_fast(float x, float y) {
    float a = fabsf(x);
    float t = __builtin_amdgcn_exp2f(a * -1.44269504088896f);       // e^-a
    float sp = 0.69314718055995f * __builtin_amdgcn_logf(1.0f + t); // ln2*log2(1+t)
    return fmaxf(x, 0.0f) - x * y + sp;
}
__device__ __forceinline__ unsigned bin_of(float l) {
    unsigned b = (unsigned)(l * 256.0f);
    return b > (BINS - 1u) ? (BINS - 1u) : b;
}

// async 16B/lane global->LDS DMA; gptr per-lane, lds ptr wave-uniform base
__device__ __forceinline__ void load_lds16(const float4* g, float4* l) {
    __builtin_amdgcn_global_load_lds((const __attribute__((address_space(1))) void*)g,
                                     (__attribute__((address_space(3))) void*)l,
                                     16, 0, 0);
}

// ---------- Phase A: sampled per-row histogram (counts only, 1/16 of data) ----------
__global__ __launch_bounds__(THREADS)
void k_sample(const float4* __restrict__ lg, const float4* __restrict__ tg,
              unsigned* __restrict__ gcnt) {
    __shared__ unsigned h[BINS * NSUB];          // 32 KB
    int t = threadIdx.x;
    for (int i = t; i < BINS * NSUB; i += THREADS) h[i] = 0;
    __syncthreads();

    int row = blockIdx.x >> 2;
    int s = blockIdx.x & 3;
    int sub = t & (NSUB - 1);

    float4 xs[4], ys[4];
#pragma unroll
    for (int i = 0; i < 4; ++i) {
        int idx = row * ROW_N4 + (s * 4 + i) * 4096 + t;
        xs[i] = lg[idx];
        ys[i] = tg[idx];
    }
#pragma unroll
    for (int i = 0; i < 4; ++i) {
        atomicAdd(&h[bin_of(loss_fast(xs[i].x, ys[i].x)) * NSUB + sub], 1u);
        atomicAdd(&h[bin_of(loss_fast(xs[i].y, ys[i].y)) * NSUB + sub], 1u);
        atomicAdd(&h[bin_of(loss_fast(xs[i].z, ys[i].z)) * NSUB + sub], 1u);
        atomicAdd(&h[bin_of(loss_fast(xs[i].w, ys[i].w)) * NSUB + sub], 1u);
    }
    __syncthreads();
    unsigned* gc = gcnt + row * BINS;
    const uint4* h4 = (const uint4*)h;
    for (int i = t; i < BINS; i += THREADS) {
        uint4 v = h4[i];
        unsigned c = v.x + v.y + v.z + v.w;
        if (c) atomicAdd(&gc[i], c);
    }
}

// ---------- Select per-row threshold T (sample quantile: 26214/16 = 1638) ----------
__global__ __launch_bounds__(THREADS)
void k_sel(const unsigned* __restrict__ gcnt, float* __restrict__ Trow) {
    const unsigned target = 1638u;
    int row = blockIdx.x;
    int t = threadIdx.x;
    __shared__ unsigned h[BINS];
    __shared__ unsigned csum[THREADS];
    for (int i = t; i < BINS; i += THREADS) h[i] = gcnt[row * BINS + i];
    __syncthreads();

    unsigned s = 0;
#pragma unroll
    for (int j = 0; j < 8; ++j) s += h[t * 8 + j];
    csum[t] = s;
    __syncthreads();
    for (int off = 1; off < THREADS; off <<= 1) {
        unsigned add = (t + off < THREADS) ? csum[t + off] : 0;
        __syncthreads();
        csum[t] += add;
        __syncthreads();
    }
    unsigned suffIncl = csum[t];
    unsigned suffExcl = (t + 1 < THREADS) ? csum[t + 1] : 0;
    if (suffExcl < target && suffIncl >= target) {
        unsigned cum = suffExcl;
        for (int j = 7; j >= 0; --j) {
            unsigned c = h[t * 8 + j];
            if (cum + c >= target) {
                Trow[row] = ((float)(t * 8 + j) + 0.5f) * (1.0f / 256.0f);
                break;
            }
            cum += c;
        }
    }
}

// ---------- Full pass: wave-private 4KB single-stream bursts via DMA ----------
__global__ __launch_bounds__(THREADS)
void k_pass(const float4* __restrict__ lg, const float4* __restrict__ tg,
            const float* __restrict__ Trow,
            double* __restrict__ rowsum, unsigned* __restrict__ rowcnt) {
    __shared__ float4 sA[4][TILE4W];    // 16 KB (lg staging, wave-private rows)
    __shared__ float4 sB[4][TILE4W];    // 16 KB (tg staging)

    int t = threadIdx.x;
    int w = t >> 6;
    int l = t & 63;
    int row = blockIdx.x >> 5;
    int chunk = blockIdx.x & 31;
    int base = row * ROW_N4 + chunk * CHUNK4 + w * WSLICE;
    float T = Trow[row];

    float lsum = 0.0f;
    unsigned lcnt = 0;

#pragma unroll
    for (int tt = 0; tt < 2; ++tt) {
        const float4* gA = lg + base + tt * TILE4W;
        const float4* gB = tg + base + tt * TILE4W;
        // 4 KB contiguous burst from lg...
#pragma unroll
        for (int i = 0; i < 4; ++i) load_lds16(gA + i * 64 + l, &sA[w][i * 64]);
        // ...then 4 KB contiguous burst from tg (single-stream runs for DRAM row locality)
#pragma unroll
        for (int i = 0; i < 4; ++i) load_lds16(gB + i * 64 + l, &sB[w][i * 64]);
        asm volatile("s_waitcnt vmcnt(0)" ::: "memory");
        __builtin_amdgcn_sched_barrier(0);
#pragma unroll
        for (int j = 0; j < 4; ++j) {
            float4 x = sA[w][j * 64 + l];
            float4 y = sB[w][j * 64 + l];
            float l0 = loss_fast(x.x, y.x);
            float l1 = loss_fast(x.y, y.y);
            float l2 = loss_fast(x.z, y.z);
            float l3 = loss_fast(x.w, y.w);
            if (l0 > T) { lsum += l0; ++lcnt; }
            if (l1 > T) { lsum += l1; ++lcnt; }
            if (l2 > T) { lsum += l2; ++lcnt; }
            if (l3 > T) { lsum += l3; ++lcnt; }
        }
    }

    // block reduction, reusing staging LDS as scratch (all waves done with it)
    __syncthreads();
    float* red_s = reinterpret_cast<float*>(sA);
    unsigned* red_c = reinterpret_cast<unsigned*>(sB);
    red_s[t] = lsum;
    red_c[t] = lcnt;
    __syncthreads();
    for (int off = THREADS / 2; off > 0; off >>= 1) {
        if (t < off) { red_s[t] += red_s[t + off]; red_c[t] += red_c[t + off]; }
        __syncthreads();
    }
    if (t == 0) {
        atomicAdd(&rowsum[row], (double)red_s[0]);
        atomicAdd(&rowcnt[row], red_c[0]);
    }
}

// ---------- Finalize: rowtot = sum_above + (k - N)*T ; mean over rows ----------
__global__ __launch_bounds__(ROWS)
void k_finalize(const double* __restrict__ rowsum, const unsigned* __restrict__ rowcnt,
                const float* __restrict__ Trow, float* __restrict__ out) {
    __shared__ double tot[ROWS];
    int r = threadIdx.x;
    double T = (double)Trow[r];
    double corr = ((double)(int)K_SEL - (double)(int)rowcnt[r]) * T;
    tot[r] = rowsum[r] + corr;
    __syncthreads();
    if (r == 0) {
        double s = 0.0;
        for (int i = 0; i < ROWS; ++i) s += tot[i];
        out[0] = (float)(s / ((double)ROWS * (double)K_SEL));
    }
}

extern "C" void kernel_launch(void* const* d_in, const int* in_sizes, int n_in,
                              void* d_out, int out_size, void* d_ws, size_t ws_size,
                              hipStream_t stream) {
    const float4* lg = (const float4*)d_in[0];
    const float4* tg = (const float4*)d_in[1];
    float* out = (float*)d_out;
    (void)in_sizes; (void)n_in; (void)out_size; (void)ws_size;

    // workspace layout
    char* ws = (char*)d_ws;
    unsigned* gcnt   = (unsigned*)(ws);                  // 64*2048*4 = 524288
    float*    Trow   = (float*)   (ws + 524288);         // 256
    double*   rowsum = (double*)  (ws + 524544);         // 512 (8-aligned)
    unsigned* rowcnt = (unsigned*)(ws + 525056);         // 256
    size_t small_bytes = 525312;

    (void)hipMemsetAsync(d_ws, 0, small_bytes, stream);

    k_sample<<<ROWS * 4, THREADS, 0, stream>>>(lg, tg, gcnt);
    k_sel<<<ROWS, THREADS, 0, stream>>>(gcnt, Trow);
    k_pass<<<ROWS * 32, THREADS, 0, stream>>>(lg, tg, Trow, rowsum, rowcnt);
    k_finalize<<<1, ROWS, 0, stream>>>(rowsum, rowcnt, Trow, out);
}